// Round 1
// baseline (1402.237 us; speedup 1.0000x reference)
//
#include <hip/hip_runtime.h>
#include <hip/hip_bf16.h>
#include <math.h>

#define H 1024
#define F 3584
#define F2 7168
#define NE 8
#define T 1024

typedef __attribute__((ext_vector_type(4))) float f32x4;
typedef __attribute__((ext_vector_type(8))) short bf16x8;

__device__ inline short f2bf(float f) {
  union { float f; unsigned u; } v; v.f = f;
  unsigned r = (v.u + 0x7FFFu + ((v.u >> 16) & 1u)) >> 16;
  return (short)r;
}

// ---------------- router: fp64 logits, top-2, per-token routing ----------------
__global__ __launch_bounds__(64) void router_k(
    const float* __restrict__ x, const float* __restrict__ gw,
    float* __restrict__ logits, int* __restrict__ cnt,
    int* __restrict__ tok_e, int* __restrict__ tok_r, float* __restrict__ tok_w)
{
  int t = blockIdx.x, l = threadIdx.x;
  const float* xr = x + (size_t)t * H;
  double acc[NE];
  #pragma unroll
  for (int e = 0; e < NE; ++e) acc[e] = 0.0;
  for (int j = 0; j < H / 64; ++j) {
    int h = j * 64 + l;
    float xv = xr[h];
    #pragma unroll
    for (int e = 0; e < NE; ++e) acc[e] += (double)xv * (double)gw[e * H + h];
  }
  #pragma unroll
  for (int off = 32; off >= 1; off >>= 1) {
    #pragma unroll
    for (int e = 0; e < NE; ++e) acc[e] += __shfl_down(acc[e], off, 64);
  }
  if (l == 0) {
    float lg[NE];
    #pragma unroll
    for (int e = 0; e < NE; ++e) { lg[e] = (float)acc[e]; logits[t * NE + e] = lg[e]; }
    int i0 = 0;
    for (int e = 1; e < NE; ++e) if (lg[e] > lg[i0]) i0 = e;          // ties -> lowest idx
    int i1 = (i0 == 0) ? 1 : 0;
    for (int e = 0; e < NE; ++e) if (e != i0 && lg[e] > lg[i1]) i1 = e;
    // top-2 renormalized softmax == sigmoid of logit difference
    float w0 = 1.f / (1.f + expf(lg[i1] - lg[i0]));
    float w1 = 1.f / (1.f + expf(lg[i0] - lg[i1]));
    int r0 = atomicAdd(&cnt[i0], 1);
    int r1 = atomicAdd(&cnt[i1], 1);
    tok_e[2 * t] = i0;     tok_r[2 * t] = r0;     tok_w[2 * t] = w0;
    tok_e[2 * t + 1] = i1; tok_r[2 * t + 1] = r1; tok_w[2 * t + 1] = w1;
  }
}

// ---------------- scan counts + build compact gather list ----------------
__global__ __launch_bounds__(1024) void build_k(
    const int* __restrict__ cnt, int* __restrict__ base,
    const int* __restrict__ tok_e, const int* __restrict__ tok_r,
    const float* __restrict__ tok_w, int* __restrict__ gtok, float* __restrict__ gws)
{
  __shared__ int sb[NE];
  if (threadIdx.x == 0) {
    int s = 0;
    for (int e = 0; e < NE; ++e) { sb[e] = s; base[e] = s; s += cnt[e]; }
  }
  __syncthreads();
  int t = threadIdx.x;
  #pragma unroll
  for (int k = 0; k < 2; ++k) {
    int e = tok_e[2 * t + k];
    int slot = sb[e] + tok_r[2 * t + k];
    gtok[slot] = t;
    gws[slot] = tok_w[2 * t + k];
  }
}

// ---------------- ffn1: gathered x @ w_gate_up[e], fused silu*up -> act (bf16) ----------------
// block = 4 waves; tile: 64 tokens x 64 f-columns (gate half + up half => N=128 weight cols)
__global__ __launch_bounds__(256) void ffn1_k(
    const float* __restrict__ x, const float* __restrict__ wgu,
    const int* __restrict__ cnt, const int* __restrict__ base,
    const int* __restrict__ gtok, unsigned short* __restrict__ act)
{
  int e = blockIdx.z;
  int n = cnt[e];
  int m0 = blockIdx.x * 64;
  if (m0 >= n) return;
  int f0 = blockIdx.y * 64;
  int wv = threadIdx.x >> 6, l = threadIdx.x & 63;
  int lr = l & 15, lg = l >> 4;
  int sb = base[e];
  const float* Wp = wgu + (size_t)e * H * F2;

  const float* ar[4];
  #pragma unroll
  for (int mf = 0; mf < 4; ++mf) {
    int sl = m0 + mf * 16 + lr;
    int tok = (sl < n) ? gtok[sb + sl] : 0;
    ar[mf] = x + (size_t)tok * H;
  }
  int fg = f0 + wv * 16 + lr;   // this wave+lane's weight column (gate); up col = fg + F

  f32x4 accg[4], accu[4];
  #pragma unroll
  for (int mf = 0; mf < 4; ++mf) { accg[mf] = (f32x4)0.f; accu[mf] = (f32x4)0.f; }

  for (int kk = 0; kk < H; kk += 32) {
    int k = kk + lg * 8;
    bf16x8 a[4];
    #pragma unroll
    for (int mf = 0; mf < 4; ++mf) {
      f32x4 p0 = *(const f32x4*)(ar[mf] + k);
      f32x4 p1 = *(const f32x4*)(ar[mf] + k + 4);
      bf16x8 t8;
      #pragma unroll
      for (int j = 0; j < 4; ++j) { t8[j] = f2bf(p0[j]); t8[4 + j] = f2bf(p1[j]); }
      a[mf] = t8;
    }
    const float* wp = Wp + (size_t)k * F2 + fg;
    bf16x8 bg, bu;
    #pragma unroll
    for (int j = 0; j < 8; ++j) {
      bg[j] = f2bf(wp[(size_t)j * F2]);
      bu[j] = f2bf(wp[(size_t)j * F2 + F]);
    }
    #pragma unroll
    for (int mf = 0; mf < 4; ++mf) {
      accg[mf] = __builtin_amdgcn_mfma_f32_16x16x32_bf16(a[mf], bg, accg[mf], 0, 0, 0);
      accu[mf] = __builtin_amdgcn_mfma_f32_16x16x32_bf16(a[mf], bu, accu[mf], 0, 0, 0);
    }
  }
  // D layout: row=(l>>4)*4+r, col=l&15
  #pragma unroll
  for (int mf = 0; mf < 4; ++mf) {
    #pragma unroll
    for (int r = 0; r < 4; ++r) {
      int sl = m0 + mf * 16 + lg * 4 + r;
      if (sl < n) {
        float g = accg[mf][r], u = accu[mf][r];
        float av = g / (1.f + expf(-g)) * u;   // silu(g)*u
        act[(size_t)(sb + sl) * F + fg] = (unsigned short)f2bf(av);
      }
    }
  }
}

// ---------------- ffn2: act @ w_down[e], weighted atomic scatter to out ----------------
// block = 4 waves; tile: 64 slots x 128 h-columns
__global__ __launch_bounds__(256) void ffn2_k(
    const unsigned short* __restrict__ act, const float* __restrict__ wd,
    const int* __restrict__ cnt, const int* __restrict__ base,
    const int* __restrict__ gtok, const float* __restrict__ gws,
    float* __restrict__ out)
{
  int e = blockIdx.z;
  int n = cnt[e];
  int m0 = blockIdx.x * 64;
  if (m0 >= n) return;
  int n0 = blockIdx.y * 128;
  int wv = threadIdx.x >> 6, l = threadIdx.x & 63;
  int lr = l & 15, lg = l >> 4;
  int sb = base[e];
  const float* Wp = wd + (size_t)e * F * H;

  const unsigned short* ar[4];
  #pragma unroll
  for (int mf = 0; mf < 4; ++mf) {
    int sl = m0 + mf * 16 + lr;
    int sc = (sl < n) ? sl : 0;
    ar[mf] = act + (size_t)(sb + sc) * F;
  }
  int c0 = n0 + (wv * 2) * 16 + lr;
  int c1 = c0 + 16;

  f32x4 acc0[4], acc1[4];
  #pragma unroll
  for (int mf = 0; mf < 4; ++mf) { acc0[mf] = (f32x4)0.f; acc1[mf] = (f32x4)0.f; }

  for (int kk = 0; kk < F; kk += 32) {
    int k = kk + lg * 8;
    bf16x8 a[4];
    #pragma unroll
    for (int mf = 0; mf < 4; ++mf) a[mf] = *(const bf16x8*)(ar[mf] + k);
    const float* wp = Wp + (size_t)k * H;
    bf16x8 b0, b1;
    #pragma unroll
    for (int j = 0; j < 8; ++j) {
      b0[j] = f2bf(wp[(size_t)j * H + c0]);
      b1[j] = f2bf(wp[(size_t)j * H + c1]);
    }
    #pragma unroll
    for (int mf = 0; mf < 4; ++mf) {
      acc0[mf] = __builtin_amdgcn_mfma_f32_16x16x32_bf16(a[mf], b0, acc0[mf], 0, 0, 0);
      acc1[mf] = __builtin_amdgcn_mfma_f32_16x16x32_bf16(a[mf], b1, acc1[mf], 0, 0, 0);
    }
  }
  #pragma unroll
  for (int mf = 0; mf < 4; ++mf) {
    #pragma unroll
    for (int r = 0; r < 4; ++r) {
      int sl = m0 + mf * 16 + lg * 4 + r;
      if (sl < n) {
        int slot = sb + sl;
        int tok = gtok[slot];
        float w = gws[slot];
        atomicAdd(&out[(size_t)tok * H + c0], w * acc0[mf][r]);
        atomicAdd(&out[(size_t)tok * H + c1], w * acc1[mf][r]);
      }
    }
  }
}

extern "C" void kernel_launch(void* const* d_in, const int* in_sizes, int n_in,
                              void* d_out, int out_size, void* d_ws, size_t ws_size,
                              hipStream_t stream)
{
  const float* x   = (const float*)d_in[0];
  const float* gw  = (const float*)d_in[1];
  const float* wgu = (const float*)d_in[2];
  const float* wdn = (const float*)d_in[3];
  float* out = (float*)d_out;
  float* logits = out + (size_t)T * H;

  char* w = (char*)d_ws;
  int*   cnt = (int*)(w);
  int*   bs  = (int*)(w + 32);
  int*   te  = (int*)(w + 64);
  int*   tr  = (int*)(w + 64 + 8192);
  float* tw  = (float*)(w + 64 + 16384);
  int*   gt  = (int*)(w + 64 + 24576);
  float* gwt = (float*)(w + 64 + 32768);
  unsigned short* act = (unsigned short*)(w + 65536);  // 2048 x 3584 bf16 = 14.68 MB

  hipMemsetAsync(d_out, 0, (size_t)T * H * sizeof(float), stream);
  hipMemsetAsync(cnt, 0, NE * sizeof(int), stream);
  router_k<<<T, 64, 0, stream>>>(x, gw, logits, cnt, te, tr, tw);
  build_k<<<1, 1024, 0, stream>>>(cnt, bs, te, tr, tw, gt, gwt);
  ffn1_k<<<dim3(16, F / 64, NE), 256, 0, stream>>>(x, wgu, cnt, bs, gt, act);
  ffn2_k<<<dim3(16, H / 128, NE), 256, 0, stream>>>(act, wdn, cnt, bs, gt, gwt, out);
}

// Round 2
// 625.774 us; speedup vs baseline: 2.2408x; 2.2408x over previous
//
#include <hip/hip_runtime.h>
#include <hip/hip_bf16.h>
#include <math.h>

#define H 1024
#define F 3584
#define F2 7168
#define NE 8
#define T 1024

typedef __attribute__((ext_vector_type(4))) float f32x4;
typedef __attribute__((ext_vector_type(8))) short bf16x8;
typedef __attribute__((ext_vector_type(4))) short bf16x4;

__device__ inline short f2bf(float f) {
  union { float f; unsigned u; } v; v.f = f;
  unsigned r = (v.u + 0x7FFFu + ((v.u >> 16) & 1u)) >> 16;
  return (short)r;
}

// ---------------- router: fp64 logits, top-2, per-token routing ----------------
__global__ __launch_bounds__(64) void router_k(
    const float* __restrict__ x, const float* __restrict__ gw,
    float* __restrict__ logits, int* __restrict__ cnt,
    int* __restrict__ tok_e, int* __restrict__ tok_r, float* __restrict__ tok_w)
{
  int t = blockIdx.x, l = threadIdx.x;
  const float* xr = x + (size_t)t * H;
  double acc[NE];
  #pragma unroll
  for (int e = 0; e < NE; ++e) acc[e] = 0.0;
  for (int j = 0; j < H / 64; ++j) {
    int h = j * 64 + l;
    float xv = xr[h];
    #pragma unroll
    for (int e = 0; e < NE; ++e) acc[e] += (double)xv * (double)gw[e * H + h];
  }
  #pragma unroll
  for (int off = 32; off >= 1; off >>= 1) {
    #pragma unroll
    for (int e = 0; e < NE; ++e) acc[e] += __shfl_down(acc[e], off, 64);
  }
  if (l == 0) {
    float lg[NE];
    #pragma unroll
    for (int e = 0; e < NE; ++e) { lg[e] = (float)acc[e]; logits[t * NE + e] = lg[e]; }
    int i0 = 0;
    for (int e = 1; e < NE; ++e) if (lg[e] > lg[i0]) i0 = e;
    int i1 = (i0 == 0) ? 1 : 0;
    for (int e = 0; e < NE; ++e) if (e != i0 && lg[e] > lg[i1]) i1 = e;
    float w0 = 1.f / (1.f + expf(lg[i1] - lg[i0]));
    float w1 = 1.f / (1.f + expf(lg[i0] - lg[i1]));
    int r0 = atomicAdd(&cnt[i0], 1);
    int r1 = atomicAdd(&cnt[i1], 1);
    tok_e[2 * t] = i0;     tok_r[2 * t] = r0;     tok_w[2 * t] = w0;
    tok_e[2 * t + 1] = i1; tok_r[2 * t + 1] = r1; tok_w[2 * t + 1] = w1;
  }
}

// ---------------- scan counts + build compact gather list ----------------
__global__ __launch_bounds__(1024) void build_k(
    const int* __restrict__ cnt, int* __restrict__ base,
    const int* __restrict__ tok_e, const int* __restrict__ tok_r,
    const float* __restrict__ tok_w, int* __restrict__ gtok, float* __restrict__ gws)
{
  __shared__ int sb[NE];
  if (threadIdx.x == 0) {
    int s = 0;
    for (int e = 0; e < NE; ++e) { sb[e] = s; base[e] = s; s += cnt[e]; }
  }
  __syncthreads();
  int t = threadIdx.x;
  #pragma unroll
  for (int k = 0; k < 2; ++k) {
    int e = tok_e[2 * t + k];
    int slot = sb[e] + tok_r[2 * t + k];
    gtok[slot] = t;
    gws[slot] = tok_w[2 * t + k];
  }
}

// ---------------- ffn1: LDS-staged, double-buffered, 64x128(out) tile ----------------
// 256 thr / 4 waves. Per K-slab(32): stage B 32k x 256wcols (128 gate + 128 up) and
// A 64rows x 32k in bf16 LDS (transposed, swizzled); 16 MFMA per wave.
__global__ __launch_bounds__(256) void ffn1_k(
    const float* __restrict__ x, const float* __restrict__ wgu,
    const int* __restrict__ cnt, const int* __restrict__ base,
    const int* __restrict__ gtok, unsigned short* __restrict__ act)
{
  int e = blockIdx.z;
  int n = cnt[e];
  int m0 = blockIdx.x * 64;
  if (m0 >= n) return;
  int f0 = blockIdx.y * 128;
  int sb = base[e];
  int tid = threadIdx.x;
  int wv = tid >> 6, l = tid & 63, lr = l & 15, lg = l >> 4;

  __shared__ __align__(16) unsigned char smem[40960];
  unsigned char* sBbuf0 = smem;              // 16KB
  unsigned char* sBbuf1 = smem + 16384;      // 16KB
  unsigned char* sAbuf0 = smem + 32768;      // 4KB
  unsigned char* sAbuf1 = smem + 36864;      // 4KB

  // ---- B staging role: thread loads 8 k-rows x 4 cols (f32x4 each row) ----
  int bcg = tid & 63;            // col-group: tile cols 4bcg..4bcg+3
  int bkg = tid >> 6;            // k-rows bkg*8 .. +8
  int c0 = 4 * bcg;
  int gc0 = (c0 < 128) ? (f0 + c0) : (F + f0 + c0 - 128);
  const float* Bg = wgu + (size_t)e * H * F2 + gc0;
  int wBoff[4];
  #pragma unroll
  for (int j = 0; j < 4; ++j) {
    int c = c0 + j;
    wBoff[j] = c * 64 + ((bkg * 16) ^ (((c >> 2) & 3) << 4));
  }

  // ---- A staging role: thread loads 1 row x 8 k (2 f32x4) ----
  int arow = tid & 63;
  int aks = ((tid >> 6) + (tid & 3)) & 3;   // rotated k-seg for conflict-free writes
  int asl = m0 + arow;
  int aslc = (asl < n) ? asl : (n - 1);
  const float* Ag = x + (size_t)gtok[sb + aslc] * H + aks * 8;
  int wAoff = arow * 64 + ((aks * 16) ^ (((arow >> 1) & 3) << 4));

  // ---- compute-side read offsets ----
  int rAoff[4], rBoff[4];
  #pragma unroll
  for (int mf = 0; mf < 4; ++mf) {
    int row = mf * 16 + lr;
    rAoff[mf] = row * 64 + ((lg * 16) ^ (((row >> 1) & 3) << 4));
  }
  #pragma unroll
  for (int cf = 0; cf < 4; ++cf) {
    int c = ((cf < 2) ? (wv * 32 + cf * 16) : (128 + wv * 32 + (cf - 2) * 16)) + lr;
    rBoff[cf] = c * 64 + ((lg * 16) ^ (((c >> 2) & 3) << 4));
  }

  f32x4 acc[4][4];
  #pragma unroll
  for (int mf = 0; mf < 4; ++mf)
    #pragma unroll
    for (int cf = 0; cf < 4; ++cf) acc[mf][cf] = (f32x4)0.f;

  f32x4 lb[8];
  f32x4 la0, la1;
  {
    const float* p = Bg + (size_t)(bkg * 8) * F2;
    #pragma unroll
    for (int i = 0; i < 8; ++i) lb[i] = *(const f32x4*)(p + (size_t)i * F2);
    la0 = *(const f32x4*)(Ag);
    la1 = *(const f32x4*)(Ag + 4);
  }

  for (int s = 0; s < 32; ++s) {
    unsigned char* sB = (s & 1) ? sBbuf1 : sBbuf0;
    unsigned char* sA = (s & 1) ? sAbuf1 : sAbuf0;
    // cvt + transpose-write current slab
    #pragma unroll
    for (int j = 0; j < 4; ++j) {
      bf16x8 p;
      #pragma unroll
      for (int i = 0; i < 8; ++i) p[i] = f2bf(lb[i][j]);
      *(bf16x8*)(sB + wBoff[j]) = p;
    }
    {
      bf16x8 pa;
      #pragma unroll
      for (int i = 0; i < 4; ++i) { pa[i] = f2bf(la0[i]); pa[4 + i] = f2bf(la1[i]); }
      *(bf16x8*)(sA + wAoff) = pa;
    }
    __syncthreads();
    // prefetch next slab (overlaps MFMA below)
    if (s + 1 < 32) {
      const float* p = Bg + (size_t)((s + 1) * 32 + bkg * 8) * F2;
      #pragma unroll
      for (int i = 0; i < 8; ++i) lb[i] = *(const f32x4*)(p + (size_t)i * F2);
      la0 = *(const f32x4*)(Ag + (s + 1) * 32);
      la1 = *(const f32x4*)(Ag + (s + 1) * 32 + 4);
    }
    bf16x8 af[4], bfr[4];
    #pragma unroll
    for (int mf = 0; mf < 4; ++mf) af[mf] = *(const bf16x8*)(sA + rAoff[mf]);
    #pragma unroll
    for (int cf = 0; cf < 4; ++cf) bfr[cf] = *(const bf16x8*)(sB + rBoff[cf]);
    #pragma unroll
    for (int mf = 0; mf < 4; ++mf)
      #pragma unroll
      for (int cf = 0; cf < 4; ++cf)
        acc[mf][cf] = __builtin_amdgcn_mfma_f32_16x16x32_bf16(af[mf], bfr[cf], acc[mf][cf], 0, 0, 0);
  }

  // epilogue: silu(gate)*up -> act (bf16); gate cf in {0,1}, up cf+2
  #pragma unroll
  for (int mf = 0; mf < 4; ++mf) {
    #pragma unroll
    for (int cf = 0; cf < 2; ++cf) {
      int fcol = f0 + wv * 32 + cf * 16 + lr;
      #pragma unroll
      for (int r = 0; r < 4; ++r) {
        int sl = m0 + mf * 16 + lg * 4 + r;
        if (sl < n) {
          float g = acc[mf][cf][r], u = acc[mf][cf + 2][r];
          float av = g / (1.f + expf(-g)) * u;
          act[(size_t)(sb + sl) * F + fcol] = (unsigned short)f2bf(av);
        }
      }
    }
  }
}

// ---------------- ffn2: LDS-staged, double-buffered, 64x128 tile, K split x2 ----------------
__global__ __launch_bounds__(256) void ffn2_k(
    const unsigned short* __restrict__ act, const float* __restrict__ wd,
    const int* __restrict__ cnt, const int* __restrict__ base,
    const int* __restrict__ gtok, const float* __restrict__ gws,
    float* __restrict__ out)
{
  int e = blockIdx.z >> 1, kh = blockIdx.z & 1;
  int n = cnt[e];
  int m0 = blockIdx.x * 64;
  if (m0 >= n) return;
  int n0 = blockIdx.y * 128;
  int sb = base[e];
  int tid = threadIdx.x;
  int wv = tid >> 6, l = tid & 63, lr = l & 15, lg = l >> 4;
  const int NS = 56;                       // 1792 / 32 slabs
  size_t kbase = (size_t)kh * 1792;

  __shared__ __align__(16) unsigned char smem[24576];
  unsigned char* sBbuf0 = smem;             // 8KB
  unsigned char* sBbuf1 = smem + 8192;      // 8KB
  unsigned char* sAbuf0 = smem + 16384;     // 4KB
  unsigned char* sAbuf1 = smem + 20480;     // 4KB

  // B staging: thread loads 4 k-rows x 4 cols
  int bcg = tid & 31;
  int bkg = tid >> 5;                      // k-rows bkg*4 .. +4
  int c0 = 4 * bcg;
  const float* Bg = wd + (size_t)e * F * H + kbase * H + (n0 + c0);
  int wBoff[4];
  #pragma unroll
  for (int j = 0; j < 4; ++j) {
    int c = c0 + j;
    wBoff[j] = c * 64 + ((bkg * 8) ^ (((c >> 2) & 3) << 4));
  }

  // A staging: thread loads 1 row x 8 k (bf16, direct 16B)
  int arow = tid & 63;
  int aks = ((tid >> 6) + (tid & 3)) & 3;
  int asl = m0 + arow;
  int aslc = (asl < n) ? asl : (n - 1);
  const unsigned short* Ag = act + (size_t)(sb + aslc) * F + kbase + aks * 8;
  int wAoff = arow * 64 + ((aks * 16) ^ (((arow >> 1) & 3) << 4));

  int rAoff[4], rBoff[2];
  #pragma unroll
  for (int mf = 0; mf < 4; ++mf) {
    int row = mf * 16 + lr;
    rAoff[mf] = row * 64 + ((lg * 16) ^ (((row >> 1) & 3) << 4));
  }
  #pragma unroll
  for (int cf = 0; cf < 2; ++cf) {
    int c = wv * 32 + cf * 16 + lr;
    rBoff[cf] = c * 64 + ((lg * 16) ^ (((c >> 2) & 3) << 4));
  }

  f32x4 acc[4][2];
  #pragma unroll
  for (int mf = 0; mf < 4; ++mf) { acc[mf][0] = (f32x4)0.f; acc[mf][1] = (f32x4)0.f; }

  f32x4 lb[4];
  bf16x8 la;
  {
    const float* p = Bg + (size_t)(bkg * 4) * H;
    #pragma unroll
    for (int i = 0; i < 4; ++i) lb[i] = *(const f32x4*)(p + (size_t)i * H);
    la = *(const bf16x8*)(Ag);
  }

  for (int s = 0; s < NS; ++s) {
    unsigned char* sB = (s & 1) ? sBbuf1 : sBbuf0;
    unsigned char* sA = (s & 1) ? sAbuf1 : sAbuf0;
    #pragma unroll
    for (int j = 0; j < 4; ++j) {
      bf16x4 p;
      #pragma unroll
      for (int i = 0; i < 4; ++i) p[i] = f2bf(lb[i][j]);
      *(bf16x4*)(sB + wBoff[j]) = p;
    }
    *(bf16x8*)(sA + wAoff) = la;
    __syncthreads();
    if (s + 1 < NS) {
      const float* p = Bg + (size_t)((s + 1) * 32 + bkg * 4) * H;
      #pragma unroll
      for (int i = 0; i < 4; ++i) lb[i] = *(const f32x4*)(p + (size_t)i * H);
      la = *(const bf16x8*)(Ag + (s + 1) * 32);
    }
    bf16x8 af[4], bfr[2];
    #pragma unroll
    for (int mf = 0; mf < 4; ++mf) af[mf] = *(const bf16x8*)(sA + rAoff[mf]);
    #pragma unroll
    for (int cf = 0; cf < 2; ++cf) bfr[cf] = *(const bf16x8*)(sB + rBoff[cf]);
    #pragma unroll
    for (int mf = 0; mf < 4; ++mf)
      #pragma unroll
      for (int cf = 0; cf < 2; ++cf)
        acc[mf][cf] = __builtin_amdgcn_mfma_f32_16x16x32_bf16(af[mf], bfr[cf], acc[mf][cf], 0, 0, 0);
  }

  #pragma unroll
  for (int mf = 0; mf < 4; ++mf) {
    #pragma unroll
    for (int cf = 0; cf < 2; ++cf) {
      int col = n0 + wv * 32 + cf * 16 + lr;
      #pragma unroll
      for (int r = 0; r < 4; ++r) {
        int sl = m0 + mf * 16 + lg * 4 + r;
        if (sl < n) {
          int slot = sb + sl;
          atomicAdd(&out[(size_t)gtok[slot] * H + col], gws[slot] * acc[mf][cf][r]);
        }
      }
    }
  }
}

extern "C" void kernel_launch(void* const* d_in, const int* in_sizes, int n_in,
                              void* d_out, int out_size, void* d_ws, size_t ws_size,
                              hipStream_t stream)
{
  const float* x   = (const float*)d_in[0];
  const float* gw  = (const float*)d_in[1];
  const float* wgu = (const float*)d_in[2];
  const float* wdn = (const float*)d_in[3];
  float* out = (float*)d_out;
  float* logits = out + (size_t)T * H;

  char* w = (char*)d_ws;
  int*   cnt = (int*)(w);
  int*   bs  = (int*)(w + 32);
  int*   te  = (int*)(w + 64);
  int*   tr  = (int*)(w + 64 + 8192);
  float* tw  = (float*)(w + 64 + 16384);
  int*   gt  = (int*)(w + 64 + 24576);
  float* gwt = (float*)(w + 64 + 32768);
  unsigned short* act = (unsigned short*)(w + 65536);  // 2048 x 3584 bf16

  hipMemsetAsync(d_out, 0, (size_t)T * H * sizeof(float), stream);
  hipMemsetAsync(cnt, 0, NE * sizeof(int), stream);
  router_k<<<T, 64, 0, stream>>>(x, gw, logits, cnt, te, tr, tw);
  build_k<<<1, 1024, 0, stream>>>(cnt, bs, te, tr, tw, gt, gwt);
  ffn1_k<<<dim3(16, F / 128, NE), 256, 0, stream>>>(x, wgu, cnt, bs, gt, act);
  ffn2_k<<<dim3(16, H / 128, NE * 2), 256, 0, stream>>>(act, wdn, cnt, bs, gt, gwt, out);
}

// Round 3
// 319.345 us; speedup vs baseline: 4.3910x; 1.9596x over previous
//
#include <hip/hip_runtime.h>
#include <hip/hip_bf16.h>
#include <math.h>

#define H 1024
#define F 3584
#define F2 7168
#define NE 8
#define T 1024

typedef __attribute__((ext_vector_type(4))) float f32x4;
typedef __attribute__((ext_vector_type(8))) short bf16x8;
typedef __attribute__((ext_vector_type(4))) short bf16x4;

__device__ inline short f2bf(float f) {
  union { float f; unsigned u; } v; v.f = f;
  unsigned r = (v.u + 0x7FFFu + ((v.u >> 16) & 1u)) >> 16;
  return (short)r;
}

// swizzled col-major-k LDS offset (bf16 tile, 32 k per col):
// write-side (col stride 4 across lanes) and read-side (col stride 1) both <=2-way.
__device__ inline int soff(int c, int k) {
  return ((c >> 1) << 7) + ((((c & 1) << 6) + (k << 1)) ^ (((c >> 2) & 7) << 4));
}

// ---------------- router: fp64 logits, top-2 ----------------
__global__ __launch_bounds__(64) void router_k(
    const float* __restrict__ x, const float* __restrict__ gw,
    float* __restrict__ logits, int* __restrict__ cnt,
    int* __restrict__ tok_e, int* __restrict__ tok_r, float* __restrict__ tok_w)
{
  int t = blockIdx.x, l = threadIdx.x;
  const float* xr = x + (size_t)t * H;
  double acc[NE];
  #pragma unroll
  for (int e = 0; e < NE; ++e) acc[e] = 0.0;
  for (int j = 0; j < H / 64; ++j) {
    int h = j * 64 + l;
    float xv = xr[h];
    #pragma unroll
    for (int e = 0; e < NE; ++e) acc[e] += (double)xv * (double)gw[e * H + h];
  }
  #pragma unroll
  for (int off = 32; off >= 1; off >>= 1) {
    #pragma unroll
    for (int e = 0; e < NE; ++e) acc[e] += __shfl_down(acc[e], off, 64);
  }
  if (l == 0) {
    float lg[NE];
    #pragma unroll
    for (int e = 0; e < NE; ++e) { lg[e] = (float)acc[e]; logits[t * NE + e] = lg[e]; }
    int i0 = 0;
    for (int e = 1; e < NE; ++e) if (lg[e] > lg[i0]) i0 = e;
    int i1 = (i0 == 0) ? 1 : 0;
    for (int e = 0; e < NE; ++e) if (e != i0 && lg[e] > lg[i1]) i1 = e;
    float w0 = 1.f / (1.f + expf(lg[i1] - lg[i0]));
    float w1 = 1.f / (1.f + expf(lg[i0] - lg[i1]));
    int r0 = atomicAdd(&cnt[i0], 1);
    int r1 = atomicAdd(&cnt[i1], 1);
    tok_e[2 * t] = i0;     tok_r[2 * t] = r0;     tok_w[2 * t] = w0;
    tok_e[2 * t + 1] = i1; tok_r[2 * t + 1] = r1; tok_w[2 * t + 1] = w1;
  }
}

// ---------------- scan + gather list ----------------
__global__ __launch_bounds__(1024) void build_k(
    const int* __restrict__ cnt, int* __restrict__ base,
    const int* __restrict__ tok_e, const int* __restrict__ tok_r,
    const float* __restrict__ tok_w, int* __restrict__ gtok, float* __restrict__ gws)
{
  __shared__ int sb[NE];
  if (threadIdx.x == 0) {
    int s = 0;
    for (int e = 0; e < NE; ++e) { sb[e] = s; base[e] = s; s += cnt[e]; }
  }
  __syncthreads();
  int t = threadIdx.x;
  #pragma unroll
  for (int k = 0; k < 2; ++k) {
    int e = tok_e[2 * t + k];
    int slot = sb[e] + tok_r[2 * t + k];
    gtok[slot] = t;
    gws[slot] = tok_w[2 * t + k];
  }
}

// ---------------- ffn1: M=64, N=128(64 gate + 64 up), BK=32, 2-deep pipeline ----------------
__global__ __launch_bounds__(256, 3) void ffn1_k(
    const float* __restrict__ x, const float* __restrict__ wgu,
    const int* __restrict__ cnt, const int* __restrict__ base,
    const int* __restrict__ gtok, unsigned short* __restrict__ act)
{
  // XCD-bijective swizzle: 7168 blocks = 8e * 56p * 16m, chunk = 896/XCD
  int wg = (blockIdx.x & 7) * 896 + (blockIdx.x >> 3);
  int mB = wg & 15;
  int ep = wg >> 4;
  int e = ep / 56, p = ep % 56;
  int n = cnt[e];
  int m0 = mB * 64;
  if (m0 >= n) return;
  int sb = base[e];
  int tid = threadIdx.x;
  int wv = tid >> 6, l = tid & 63, lr = l & 15, lg = l >> 4;

  __shared__ __align__(16) unsigned char smem[24576];
  unsigned char* sB0 = smem;
  unsigned char* sB1 = smem + 8192;
  unsigned char* sA0 = smem + 16384;
  unsigned char* sA1 = smem + 20480;

  // B staging: thread -> cols 4g..4g+3, k-rows 4kg..4kg+3
  int g = tid & 31, kg = tid >> 5;
  int tc0 = 4 * g;
  int gc = (tc0 < 64) ? (p * 64 + tc0) : (F + p * 64 + tc0 - 64);
  const float* Bg = wgu + (size_t)e * H * F2 + gc;
  int wB[4];
  #pragma unroll
  for (int j = 0; j < 4; ++j) wB[j] = soff(tc0 + j, kg * 4);

  // A staging: thread -> 1 row x 8 k
  int arow = tid & 63, aseg = tid >> 6;
  int asl = m0 + arow;
  int aslc = (asl < n) ? asl : (n - 1);
  const float* Ag = x + (size_t)gtok[sb + aslc] * H + aseg * 8;
  int wA = soff(arow, aseg * 8);

  // fragment read offsets
  int rA[4];
  #pragma unroll
  for (int mf = 0; mf < 4; ++mf) rA[mf] = soff(mf * 16 + lr, lg * 8);
  int rB0o = soff(wv * 16 + lr, lg * 8);
  int rB1o = soff(64 + wv * 16 + lr, lg * 8);

  f32x4 acc[4][2];
  #pragma unroll
  for (int mf = 0; mf < 4; ++mf) { acc[mf][0] = (f32x4)0.f; acc[mf][1] = (f32x4)0.f; }

  f32x4 b0[4], b1[4], a0[2], a1[2];

#define L1(S, B, A) { \
    const float* bp = Bg + (size_t)((S) * 32 + kg * 4) * F2; \
    B[0] = *(const f32x4*)bp;            B[1] = *(const f32x4*)(bp + F2); \
    B[2] = *(const f32x4*)(bp + 2 * F2); B[3] = *(const f32x4*)(bp + 3 * F2); \
    const float* ap = Ag + (S) * 32; \
    A[0] = *(const f32x4*)ap; A[1] = *(const f32x4*)(ap + 4); }

#define P1(B, A, sB, sA, SN, DO) { \
    _Pragma("unroll") for (int j = 0; j < 4; ++j) { \
      bf16x4 w; w[0] = f2bf(B[0][j]); w[1] = f2bf(B[1][j]); \
      w[2] = f2bf(B[2][j]); w[3] = f2bf(B[3][j]); \
      *(bf16x4*)((sB) + wB[j]) = w; } \
    { bf16x8 w; _Pragma("unroll") for (int i2 = 0; i2 < 4; ++i2) { \
        w[i2] = f2bf(A[0][i2]); w[4 + i2] = f2bf(A[1][i2]); } \
      *(bf16x8*)((sA) + wA) = w; } \
    asm volatile("s_waitcnt lgkmcnt(0)" ::: "memory"); \
    __builtin_amdgcn_s_barrier(); \
    if (DO) { L1(SN, B, A); } \
    bf16x8 bf0 = *(const bf16x8*)((sB) + rB0o); \
    bf16x8 bf1 = *(const bf16x8*)((sB) + rB1o); \
    _Pragma("unroll") for (int mf = 0; mf < 4; ++mf) { \
      bf16x8 af = *(const bf16x8*)((sA) + rA[mf]); \
      acc[mf][0] = __builtin_amdgcn_mfma_f32_16x16x32_bf16(af, bf0, acc[mf][0], 0, 0, 0); \
      acc[mf][1] = __builtin_amdgcn_mfma_f32_16x16x32_bf16(af, bf1, acc[mf][1], 0, 0, 0); } }

  L1(0, b0, a0);
  L1(1, b1, a1);

  for (int it = 0; it < 16; ++it) {
    int s = 2 * it;
    bool more = (it < 15);
    P1(b0, a0, sB0, sA0, s + 2, more);
    P1(b1, a1, sB1, sA1, s + 3, more);
  }
#undef L1
#undef P1

  int fcol = p * 64 + wv * 16 + lr;
  #pragma unroll
  for (int mf = 0; mf < 4; ++mf) {
    #pragma unroll
    for (int r = 0; r < 4; ++r) {
      int sl = m0 + mf * 16 + lg * 4 + r;
      if (sl < n) {
        float gg = acc[mf][0][r], u = acc[mf][1][r];
        act[(size_t)(sb + sl) * F + fcol] = (unsigned short)f2bf(gg / (1.f + expf(-gg)) * u);
      }
    }
  }
}

// ---------------- ffn2: M=64, N=128, BK=32, K-split x2, 2-deep pipeline ----------------
__global__ __launch_bounds__(256, 3) void ffn2_k(
    const unsigned short* __restrict__ act, const float* __restrict__ wd,
    const int* __restrict__ cnt, const int* __restrict__ base,
    const int* __restrict__ gtok, const float* __restrict__ gws,
    float* __restrict__ out)
{
  // 2048 blocks = 8e * 2kh * 8p * 16m, chunk = 256/XCD
  int wg = (blockIdx.x & 7) * 256 + (blockIdx.x >> 3);
  int mB = wg & 15;
  int r2 = wg >> 4;
  int p = r2 & 7;
  int ekh = r2 >> 3;
  int kh = ekh & 1, e = ekh >> 1;
  int n = cnt[e];
  int m0 = mB * 64;
  if (m0 >= n) return;
  int sb = base[e];
  int tid = threadIdx.x;
  int wv = tid >> 6, l = tid & 63, lr = l & 15, lg = l >> 4;
  const int kbase = kh * 1792;

  __shared__ __align__(16) unsigned char smem[24576];
  unsigned char* sB0 = smem;
  unsigned char* sB1 = smem + 8192;
  unsigned char* sA0 = smem + 16384;
  unsigned char* sA1 = smem + 20480;

  int g = tid & 31, kg = tid >> 5;
  int tc0 = 4 * g;
  const float* Bg = wd + (size_t)e * F * H + (size_t)kbase * H + p * 128 + tc0;
  int wB[4];
  #pragma unroll
  for (int j = 0; j < 4; ++j) wB[j] = soff(tc0 + j, kg * 4);

  int arow = tid & 63, aseg = tid >> 6;
  int asl = m0 + arow;
  int aslc = (asl < n) ? asl : (n - 1);
  const unsigned short* Ag = act + (size_t)(sb + aslc) * F + kbase + aseg * 8;
  int wA = soff(arow, aseg * 8);

  int rA[4];
  #pragma unroll
  for (int mf = 0; mf < 4; ++mf) rA[mf] = soff(mf * 16 + lr, lg * 8);
  int rB0o = soff(wv * 16 + lr, lg * 8);
  int rB1o = soff(64 + wv * 16 + lr, lg * 8);

  f32x4 acc[4][2];
  #pragma unroll
  for (int mf = 0; mf < 4; ++mf) { acc[mf][0] = (f32x4)0.f; acc[mf][1] = (f32x4)0.f; }

  f32x4 b0[4], b1[4];
  bf16x8 a0, a1;

#define L2K(S, B, A) { \
    const float* bp = Bg + (size_t)((S) * 32 + kg * 4) * H; \
    B[0] = *(const f32x4*)bp;           B[1] = *(const f32x4*)(bp + H); \
    B[2] = *(const f32x4*)(bp + 2 * H); B[3] = *(const f32x4*)(bp + 3 * H); \
    A = *(const bf16x8*)(Ag + (S) * 32); }

#define P2(B, A, sB, sA, SN, DO) { \
    _Pragma("unroll") for (int j = 0; j < 4; ++j) { \
      bf16x4 w; w[0] = f2bf(B[0][j]); w[1] = f2bf(B[1][j]); \
      w[2] = f2bf(B[2][j]); w[3] = f2bf(B[3][j]); \
      *(bf16x4*)((sB) + wB[j]) = w; } \
    *(bf16x8*)((sA) + wA) = A; \
    asm volatile("s_waitcnt lgkmcnt(0)" ::: "memory"); \
    __builtin_amdgcn_s_barrier(); \
    if (DO) { L2K(SN, B, A); } \
    bf16x8 bf0 = *(const bf16x8*)((sB) + rB0o); \
    bf16x8 bf1 = *(const bf16x8*)((sB) + rB1o); \
    _Pragma("unroll") for (int mf = 0; mf < 4; ++mf) { \
      bf16x8 af = *(const bf16x8*)((sA) + rA[mf]); \
      acc[mf][0] = __builtin_amdgcn_mfma_f32_16x16x32_bf16(af, bf0, acc[mf][0], 0, 0, 0); \
      acc[mf][1] = __builtin_amdgcn_mfma_f32_16x16x32_bf16(af, bf1, acc[mf][1], 0, 0, 0); } }

  L2K(0, b0, a0);
  L2K(1, b1, a1);

  for (int it = 0; it < 28; ++it) {
    int s = 2 * it;
    bool more = (it < 27);
    P2(b0, a0, sB0, sA0, s + 2, more);
    P2(b1, a1, sB1, sA1, s + 3, more);
  }
#undef L2K
#undef P2

  #pragma unroll
  for (int mf = 0; mf < 4; ++mf) {
    #pragma unroll
    for (int r = 0; r < 4; ++r) {
      int sl = m0 + mf * 16 + lg * 4 + r;
      if (sl < n) {
        int slot = sb + sl;
        int tok = gtok[slot];
        float w = gws[slot];
        atomicAdd(&out[(size_t)tok * H + p * 128 + wv * 16 + lr], w * acc[mf][0][r]);
        atomicAdd(&out[(size_t)tok * H + p * 128 + 64 + wv * 16 + lr], w * acc[mf][1][r]);
      }
    }
  }
}

extern "C" void kernel_launch(void* const* d_in, const int* in_sizes, int n_in,
                              void* d_out, int out_size, void* d_ws, size_t ws_size,
                              hipStream_t stream)
{
  const float* x   = (const float*)d_in[0];
  const float* gw  = (const float*)d_in[1];
  const float* wgu = (const float*)d_in[2];
  const float* wdn = (const float*)d_in[3];
  float* out = (float*)d_out;
  float* logits = out + (size_t)T * H;

  char* w = (char*)d_ws;
  int*   cnt = (int*)(w);
  int*   bs  = (int*)(w + 32);
  int*   te  = (int*)(w + 64);
  int*   tr  = (int*)(w + 64 + 8192);
  float* tw  = (float*)(w + 64 + 16384);
  int*   gt  = (int*)(w + 64 + 24576);
  float* gwt = (float*)(w + 64 + 32768);
  unsigned short* act = (unsigned short*)(w + 65536);  // 2048 x 3584 bf16

  hipMemsetAsync(d_out, 0, (size_t)T * H * sizeof(float), stream);
  hipMemsetAsync(cnt, 0, NE * sizeof(int), stream);
  router_k<<<T, 64, 0, stream>>>(x, gw, logits, cnt, te, tr, tw);
  build_k<<<1, 1024, 0, stream>>>(cnt, bs, te, tr, tw, gt, gwt);
  ffn1_k<<<7168, 256, 0, stream>>>(x, wgu, cnt, bs, gt, act);
  ffn2_k<<<2048, 256, 0, stream>>>(act, wdn, cnt, bs, gt, gwt, out);
}

// Round 4
// 295.577 us; speedup vs baseline: 4.7441x; 1.0804x over previous
//
#include <hip/hip_runtime.h>
#include <hip/hip_bf16.h>
#include <math.h>

#define H 1024
#define F 3584
#define F2 7168
#define NE 8
#define T 1024

typedef __attribute__((ext_vector_type(4))) float f32x4;
typedef __attribute__((ext_vector_type(8))) short bf16x8;
typedef __attribute__((ext_vector_type(2))) unsigned u32x2;
typedef __attribute__((ext_vector_type(4))) unsigned u32x4;

__device__ inline short f2bf(float f) {
  union { float f; unsigned u; } v; v.f = f;
  unsigned r = (v.u + 0x7FFFu + ((v.u >> 16) & 1u)) >> 16;
  return (short)r;
}

__device__ inline unsigned pkbf(float a, float b) {
  unsigned r;
  asm("v_cvt_pk_bf16_f32 %0, %1, %2" : "=v"(r) : "v"(a), "v"(b));
  return r;
}

// swizzled col-major-k LDS offset (bf16 tile, 32 k per col)
__device__ inline int soff(int c, int k) {
  return ((c >> 1) << 7) + ((((c & 1) << 6) + (k << 1)) ^ (((c >> 2) & 7) << 4));
}

// ---------------- router: fp64 logits, top-2 ----------------
__global__ __launch_bounds__(64) void router_k(
    const float* __restrict__ x, const float* __restrict__ gw,
    float* __restrict__ logits, int* __restrict__ cnt,
    int* __restrict__ tok_e, int* __restrict__ tok_r, float* __restrict__ tok_w)
{
  int t = blockIdx.x, l = threadIdx.x;
  const float* xr = x + (size_t)t * H;
  double acc[NE];
  #pragma unroll
  for (int e = 0; e < NE; ++e) acc[e] = 0.0;
  for (int j = 0; j < H / 64; ++j) {
    int h = j * 64 + l;
    float xv = xr[h];
    #pragma unroll
    for (int e = 0; e < NE; ++e) acc[e] += (double)xv * (double)gw[e * H + h];
  }
  #pragma unroll
  for (int off = 32; off >= 1; off >>= 1) {
    #pragma unroll
    for (int e = 0; e < NE; ++e) acc[e] += __shfl_down(acc[e], off, 64);
  }
  if (l == 0) {
    float lg[NE];
    #pragma unroll
    for (int e = 0; e < NE; ++e) { lg[e] = (float)acc[e]; logits[t * NE + e] = lg[e]; }
    int i0 = 0;
    for (int e = 1; e < NE; ++e) if (lg[e] > lg[i0]) i0 = e;
    int i1 = (i0 == 0) ? 1 : 0;
    for (int e = 0; e < NE; ++e) if (e != i0 && lg[e] > lg[i1]) i1 = e;
    float w0 = 1.f / (1.f + expf(lg[i1] - lg[i0]));
    float w1 = 1.f / (1.f + expf(lg[i0] - lg[i1]));
    int r0 = atomicAdd(&cnt[i0], 1);
    int r1 = atomicAdd(&cnt[i1], 1);
    tok_e[2 * t] = i0;     tok_r[2 * t] = r0;     tok_w[2 * t] = w0;
    tok_e[2 * t + 1] = i1; tok_r[2 * t + 1] = r1; tok_w[2 * t + 1] = w1;
  }
}

// ---------------- scan + gather list ----------------
__global__ __launch_bounds__(1024) void build_k(
    const int* __restrict__ cnt, int* __restrict__ base,
    const int* __restrict__ tok_e, const int* __restrict__ tok_r,
    const float* __restrict__ tok_w, int* __restrict__ gtok, float* __restrict__ gws)
{
  __shared__ int sb[NE];
  if (threadIdx.x == 0) {
    int s = 0;
    for (int e = 0; e < NE; ++e) { sb[e] = s; base[e] = s; s += cnt[e]; }
  }
  __syncthreads();
  int t = threadIdx.x;
  #pragma unroll
  for (int k = 0; k < 2; ++k) {
    int e = tok_e[2 * t + k];
    int slot = sb[e] + tok_r[2 * t + k];
    gtok[slot] = t;
    gws[slot] = tok_w[2 * t + k];
  }
}

// ---------------- ffn1: M=64, N=128(64g+64u), BK=32, 3-deep pipeline ----------------
__global__ __launch_bounds__(256, 3) void ffn1_k(
    const float* __restrict__ x, const float* __restrict__ wgu,
    const int* __restrict__ cnt, const int* __restrict__ base,
    const int* __restrict__ gtok, unsigned short* __restrict__ act)
{
  // XCD-bijective swizzle: 7168 = 8 XCD * 896; mB innermost -> same weight panel per XCD
  int wg = (blockIdx.x & 7) * 896 + (blockIdx.x >> 3);
  int mB = wg & 15;
  int ep = wg >> 4;
  int e = ep / 56, p = ep % 56;
  int n = cnt[e];
  int m0 = mB * 64;
  if (m0 >= n) return;
  int sb = base[e];
  int tid = threadIdx.x;
  int wv = tid >> 6, l = tid & 63, lr = l & 15, lg = l >> 4;

  __shared__ __align__(16) unsigned char smem[36864];
  unsigned char* sB0 = smem;
  unsigned char* sB1 = smem + 8192;
  unsigned char* sB2 = smem + 16384;
  unsigned char* sA0 = smem + 24576;
  unsigned char* sA1 = smem + 28672;
  unsigned char* sA2 = smem + 32768;

  // B staging: thread -> cols 4g..4g+3, k-rows 4kg..4kg+3
  int g = tid & 31, kg = tid >> 5;
  int tc0 = 4 * g;
  int gc = (tc0 < 64) ? (p * 64 + tc0) : (F + p * 64 + tc0 - 64);
  const float* Bg = wgu + (size_t)e * H * F2 + gc;
  int wB[4];
  #pragma unroll
  for (int j = 0; j < 4; ++j) wB[j] = soff(tc0 + j, kg * 4);

  // A staging: thread -> 1 row x 8 k
  int arow = tid & 63, aseg = tid >> 6;
  int asl = m0 + arow;
  int aslc = (asl < n) ? asl : (n - 1);
  const float* Ag = x + (size_t)gtok[sb + aslc] * H + aseg * 8;
  int wA = soff(arow, aseg * 8);

  int rA[4];
  #pragma unroll
  for (int mf = 0; mf < 4; ++mf) rA[mf] = soff(mf * 16 + lr, lg * 8);
  int rB0o = soff(wv * 16 + lr, lg * 8);
  int rB1o = soff(64 + wv * 16 + lr, lg * 8);

  f32x4 acc[4][2];
  #pragma unroll
  for (int mf = 0; mf < 4; ++mf) { acc[mf][0] = (f32x4)0.f; acc[mf][1] = (f32x4)0.f; }

  f32x4 b0[4], b1[4], b2[4], a0[2], a1[2], a2[2];

#define L1(S, B, A) { \
    const float* bp = Bg + (size_t)((S) * 32 + kg * 4) * F2; \
    B[0] = *(const f32x4*)bp;            B[1] = *(const f32x4*)(bp + F2); \
    B[2] = *(const f32x4*)(bp + 2 * F2); B[3] = *(const f32x4*)(bp + 3 * F2); \
    const float* ap = Ag + (S) * 32; \
    A[0] = *(const f32x4*)ap; A[1] = *(const f32x4*)(ap + 4); }

#define P1(B, A, sB, sA, SN, DO) { \
    _Pragma("unroll") for (int j = 0; j < 4; ++j) { \
      u32x2 w; w[0] = pkbf(B[0][j], B[1][j]); w[1] = pkbf(B[2][j], B[3][j]); \
      *(u32x2*)((sB) + wB[j]) = w; } \
    { u32x4 w; w[0] = pkbf(A[0][0], A[0][1]); w[1] = pkbf(A[0][2], A[0][3]); \
      w[2] = pkbf(A[1][0], A[1][1]); w[3] = pkbf(A[1][2], A[1][3]); \
      *(u32x4*)((sA) + wA) = w; } \
    if (DO) { L1(SN, B, A); } \
    asm volatile("s_waitcnt lgkmcnt(0)" ::: "memory"); \
    __builtin_amdgcn_s_barrier(); \
    bf16x8 bf0 = *(const bf16x8*)((sB) + rB0o); \
    bf16x8 bf1 = *(const bf16x8*)((sB) + rB1o); \
    _Pragma("unroll") for (int mf = 0; mf < 4; ++mf) { \
      bf16x8 af = *(const bf16x8*)((sA) + rA[mf]); \
      acc[mf][0] = __builtin_amdgcn_mfma_f32_16x16x32_bf16(af, bf0, acc[mf][0], 0, 0, 0); \
      acc[mf][1] = __builtin_amdgcn_mfma_f32_16x16x32_bf16(af, bf1, acc[mf][1], 0, 0, 0); } }

  L1(0, b0, a0);
  L1(1, b1, a1);
  L1(2, b2, a2);

  for (int it = 0; it < 10; ++it) {
    int s = 3 * it;
    P1(b0, a0, sB0, sA0, s + 3, true);
    P1(b1, a1, sB1, sA1, s + 4, true);
    P1(b2, a2, sB2, sA2, s + 5, (it < 9));
  }
  P1(b0, a0, sB0, sA0, 0, false);
  P1(b1, a1, sB1, sA1, 0, false);
#undef L1
#undef P1

  int fcol = p * 64 + wv * 16 + lr;
  #pragma unroll
  for (int mf = 0; mf < 4; ++mf) {
    #pragma unroll
    for (int r = 0; r < 4; ++r) {
      int sl = m0 + mf * 16 + lg * 4 + r;
      if (sl < n) {
        float gg = acc[mf][0][r], u = acc[mf][1][r];
        act[(size_t)(sb + sl) * F + fcol] = (unsigned short)f2bf(gg / (1.f + expf(-gg)) * u);
      }
    }
  }
}

// ---------------- ffn2: M=64, N=128, BK=32, K-split x2, 3-deep pipeline ----------------
__global__ __launch_bounds__(256, 3) void ffn2_k(
    const unsigned short* __restrict__ act, const float* __restrict__ wd,
    const int* __restrict__ cnt, const int* __restrict__ base,
    const int* __restrict__ gtok, const float* __restrict__ gws,
    float* __restrict__ out)
{
  // 2048 blocks = 8 XCD * 256
  int wg = (blockIdx.x & 7) * 256 + (blockIdx.x >> 3);
  int mB = wg & 15;
  int r2 = wg >> 4;
  int p = r2 & 7;
  int ekh = r2 >> 3;
  int kh = ekh & 1, e = ekh >> 1;
  int n = cnt[e];
  int m0 = mB * 64;
  if (m0 >= n) return;
  int sb = base[e];
  int tid = threadIdx.x;
  int wv = tid >> 6, l = tid & 63, lr = l & 15, lg = l >> 4;
  const int kbase = kh * 1792;

  __shared__ __align__(16) unsigned char smem[36864];
  unsigned char* sB0 = smem;
  unsigned char* sB1 = smem + 8192;
  unsigned char* sB2 = smem + 16384;
  unsigned char* sA0 = smem + 24576;
  unsigned char* sA1 = smem + 28672;
  unsigned char* sA2 = smem + 32768;

  int g = tid & 31, kg = tid >> 5;
  int tc0 = 4 * g;
  const float* Bg = wd + (size_t)e * F * H + (size_t)kbase * H + p * 128 + tc0;
  int wB[4];
  #pragma unroll
  for (int j = 0; j < 4; ++j) wB[j] = soff(tc0 + j, kg * 4);

  int arow = tid & 63, aseg = tid >> 6;
  int asl = m0 + arow;
  int aslc = (asl < n) ? asl : (n - 1);
  const unsigned short* Ag = act + (size_t)(sb + aslc) * F + kbase + aseg * 8;
  int wA = soff(arow, aseg * 8);

  int rA[4];
  #pragma unroll
  for (int mf = 0; mf < 4; ++mf) rA[mf] = soff(mf * 16 + lr, lg * 8);
  int rB0o = soff(wv * 16 + lr, lg * 8);
  int rB1o = soff(64 + wv * 16 + lr, lg * 8);

  f32x4 acc[4][2];
  #pragma unroll
  for (int mf = 0; mf < 4; ++mf) { acc[mf][0] = (f32x4)0.f; acc[mf][1] = (f32x4)0.f; }

  f32x4 b0[4], b1[4], b2[4];
  bf16x8 a0, a1, a2;

#define L2K(S, B, A) { \
    const float* bp = Bg + (size_t)((S) * 32 + kg * 4) * H; \
    B[0] = *(const f32x4*)bp;           B[1] = *(const f32x4*)(bp + H); \
    B[2] = *(const f32x4*)(bp + 2 * H); B[3] = *(const f32x4*)(bp + 3 * H); \
    A = *(const bf16x8*)(Ag + (S) * 32); }

#define P2(B, A, sB, sA, SN, DO) { \
    _Pragma("unroll") for (int j = 0; j < 4; ++j) { \
      u32x2 w; w[0] = pkbf(B[0][j], B[1][j]); w[1] = pkbf(B[2][j], B[3][j]); \
      *(u32x2*)((sB) + wB[j]) = w; } \
    *(bf16x8*)((sA) + wA) = A; \
    if (DO) { L2K(SN, B, A); } \
    asm volatile("s_waitcnt lgkmcnt(0)" ::: "memory"); \
    __builtin_amdgcn_s_barrier(); \
    bf16x8 bf0 = *(const bf16x8*)((sB) + rB0o); \
    bf16x8 bf1 = *(const bf16x8*)((sB) + rB1o); \
    _Pragma("unroll") for (int mf = 0; mf < 4; ++mf) { \
      bf16x8 af = *(const bf16x8*)((sA) + rA[mf]); \
      acc[mf][0] = __builtin_amdgcn_mfma_f32_16x16x32_bf16(af, bf0, acc[mf][0], 0, 0, 0); \
      acc[mf][1] = __builtin_amdgcn_mfma_f32_16x16x32_bf16(af, bf1, acc[mf][1], 0, 0, 0); } }

  L2K(0, b0, a0);
  L2K(1, b1, a1);
  L2K(2, b2, a2);

  for (int it = 0; it < 18; ++it) {
    int s = 3 * it;
    P2(b0, a0, sB0, sA0, s + 3, true);
    P2(b1, a1, sB1, sA1, s + 4, true);
    P2(b2, a2, sB2, sA2, s + 5, (it < 17));
  }
  P2(b0, a0, sB0, sA0, 0, false);
  P2(b1, a1, sB1, sA1, 0, false);
#undef L2K
#undef P2

  #pragma unroll
  for (int mf = 0; mf < 4; ++mf) {
    #pragma unroll
    for (int r = 0; r < 4; ++r) {
      int sl = m0 + mf * 16 + lg * 4 + r;
      if (sl < n) {
        int slot = sb + sl;
        int tok = gtok[slot];
        float w = gws[slot];
        atomicAdd(&out[(size_t)tok * H + p * 128 + wv * 16 + lr], w * acc[mf][0][r]);
        atomicAdd(&out[(size_t)tok * H + p * 128 + 64 + wv * 16 + lr], w * acc[mf][1][r]);
      }
    }
  }
}

extern "C" void kernel_launch(void* const* d_in, const int* in_sizes, int n_in,
                              void* d_out, int out_size, void* d_ws, size_t ws_size,
                              hipStream_t stream)
{
  const float* x   = (const float*)d_in[0];
  const float* gw  = (const float*)d_in[1];
  const float* wgu = (const float*)d_in[2];
  const float* wdn = (const float*)d_in[3];
  float* out = (float*)d_out;
  float* logits = out + (size_t)T * H;

  char* w = (char*)d_ws;
  int*   cnt = (int*)(w);
  int*   bs  = (int*)(w + 32);
  int*   te  = (int*)(w + 64);
  int*   tr  = (int*)(w + 64 + 8192);
  float* tw  = (float*)(w + 64 + 16384);
  int*   gt  = (int*)(w + 64 + 24576);
  float* gwt = (float*)(w + 64 + 32768);
  unsigned short* act = (unsigned short*)(w + 65536);  // 2048 x 3584 bf16

  hipMemsetAsync(d_out, 0, (size_t)T * H * sizeof(float), stream);
  hipMemsetAsync(cnt, 0, NE * sizeof(int), stream);
  router_k<<<T, 64, 0, stream>>>(x, gw, logits, cnt, te, tr, tw);
  build_k<<<1, 1024, 0, stream>>>(cnt, bs, te, tr, tw, gt, gwt);
  ffn1_k<<<7168, 256, 0, stream>>>(x, wgu, cnt, bs, gt, act);
  ffn2_k<<<2048, 256, 0, stream>>>(act, wdn, cnt, bs, gt, gwt, out);
}